// Round 7
// baseline (293.434 us; speedup 1.0000x reference)
//
#include <hip/hip_runtime.h>
#include <stdint.h>

#define NN 65536
#define NB 512
#define NPG 128
#define NE 262144
#define EPG 512
#define HD 256
#define BN_EPS 1e-5f

typedef unsigned short u16;
typedef float f32x4 __attribute__((ext_vector_type(4)));
typedef __bf16 bf16x8 __attribute__((ext_vector_type(8)));
typedef unsigned short u16x8 __attribute__((ext_vector_type(8)));
typedef unsigned short u16x4 __attribute__((ext_vector_type(4)));

__device__ __forceinline__ float b2f(u16 u){
  union { unsigned i; float f; } x; x.i = ((unsigned)u) << 16; return x.f;
}
__device__ __forceinline__ u16 f2b(float f){
  union { float f; unsigned i; } x; x.f = f;
  unsigned r = x.i + 0x7fffu + ((x.i >> 16) & 1u);   // RNE
  return (u16)(r >> 16);
}
// fast tanh: 1 - 2/(1+e^{2x})
__device__ __forceinline__ float ftanh(float x){
  float e = __expf(2.0f * x);
  return 1.0f - 2.0f * __builtin_amdgcn_rcpf(e + 1.0f);
}
// 8 u8 counts -> bf16x8 (exact: ints <= 255, low mantissa bits zero)
__device__ __forceinline__ bf16x8 u8x8_to_bf16x8(unsigned d0, unsigned d1){
  u16x8 r;
  #pragma unroll
  for (int b = 0; b < 4; b++){
    union { float f; unsigned u; } x, y;
    x.f = (float)((d0 >> (b * 8)) & 255u);
    y.f = (float)((d1 >> (b * 8)) & 255u);
    r[b] = (u16)(x.u >> 16);
    r[4 + b] = (u16)(y.u >> 16);
  }
  return *(bf16x8*)&r;
}

// ---------------------------------------------------------------------------
// Pack all weights into bf16 images, layout Wt[col][K].
// ---------------------------------------------------------------------------
__global__ void __launch_bounds__(256) pack_all(
    const float* __restrict__ w0_1, const float* __restrict__ w0_2,
    const float* __restrict__ wl1, const float* __restrict__ wl2,
    const float* __restrict__ c1w,
    u16* i01, u16* i02, u16* il1a, u16* il1b, u16* il2a, u16* il2b, u16* ic1)
{
  const int seg = blockIdx.y;
  const int idx = blockIdx.x * 256 + threadIdx.x;
  const float* W; u16* img; int K = 256;
  switch (seg){
    case 0: W = w0_1;        img = i01;  K = 128; break;
    case 1: W = w0_2;        img = i02;  break;
    case 2: W = wl1;         img = il1a; break;
    case 3: W = wl1 + 65536; img = il1b; break;
    case 4: W = wl2;         img = il2a; break;
    case 5: W = wl2 + 65536; img = il2b; break;
    default: W = c1w;        img = ic1;  break;
  }
  if (idx >= K * 256) return;
  int col = idx / K, k = idx - col * K;
  img[idx] = f2b(W[(size_t)k * 256 + col]);
}

// ---------------------------------------------------------------------------
// Fused GIN layer, all-MFMA. Block = graph, 512 threads (8 waves).
// LDS: ht (h tile, [128][KIN] bf16 swz) | G1T ([256 c][128 n] bf16 swz,
//      reused as z1 [128 n][256 c] swz) | A_u8 ([128 d][128 s] swz).
// GEMM1 (natural): G1 = h@W1 -> G1T b64 stores.
// agg (swapped):   z1^T = G1^T @ (I+A)^T -> z1 b64 stores (bias+relu).
// GEMM2 (swapped): Y^T = W2^T @ z1^T -> 8B global stores + BN stats.
// ---------------------------------------------------------------------------
template<int KIN, int MODE>
__global__ void __launch_bounds__(512, 2) layer_kernel(
    const void* __restrict__ hin_, const int* __restrict__ ei,
    const float* __restrict__ sc, const float* __restrict__ sh,
    const u16* __restrict__ w1img, const float* __restrict__ b1,
    const u16* __restrict__ w2img, const float* __restrict__ b2,
    u16* __restrict__ Y, float* __restrict__ pS, float* __restrict__ pQ)
{
  __shared__ __align__(16) char smem[KIN * 256 + 65536 + 16384];
  char* ht  = smem;                       // 128 x KIN bf16, swz (row&7)<<4
  char* g1t = smem + KIN * 256;           // G1T then z1
  unsigned* A32 = (unsigned*)(smem + KIN * 256 + 65536);
  char* Ab = (char*)A32;

  const int g = blockIdx.x, tid = threadIdx.x;
  const int lane = tid & 63, wid = tid >> 6;
  const int l15 = lane & 15, lk = (lane >> 4) * 8;
  const int c0 = wid * 32;

  // ---- zero A ----
  #pragma unroll
  for (int i = 0; i < 8; i++) A32[tid + i * 512] = 0u;
  __syncthreads();

  // ---- build (I+A) as u8, swizzled; 1 edge/thread ----
  {
    int s = ei[g * EPG + tid] & (NPG - 1);
    int d = ei[NE + g * EPG + tid] & (NPG - 1);
    unsigned byte = ((unsigned)((d << 7) | (s & ~3))) ^ ((unsigned)((d & 7) << 4));
    atomicAdd(&A32[byte >> 2], 1u << ((s & 3) * 8));
  }
  if (tid < NPG){
    int n = tid;
    unsigned byte = ((unsigned)((n << 7) | (n & ~3))) ^ ((unsigned)((n & 7) << 4));
    atomicAdd(&A32[byte >> 2], 1u << ((n & 3) * 8));
  }

  // ---- stage h tile (swizzled bf16) ----
  if constexpr (MODE == 0){
    const float* hin = (const float*)hin_;
    #pragma unroll
    for (int i = 0; i < 4; i++){
      int idx = tid + i * 512;
      int row = idx >> 4, c8 = idx & 15;
      const float* p = hin + (size_t)(g * NPG + row) * KIN + c8 * 8;
      float4 v0 = *(const float4*)p;
      float4 v1 = *(const float4*)(p + 4);
      u16x8 o;
      o[0] = f2b(v0.x); o[1] = f2b(v0.y); o[2] = f2b(v0.z); o[3] = f2b(v0.w);
      o[4] = f2b(v1.x); o[5] = f2b(v1.y); o[6] = f2b(v1.z); o[7] = f2b(v1.w);
      unsigned byte = ((unsigned)(row * (KIN * 2) + c8 * 16)) ^ ((unsigned)((row & 7) << 4));
      *(u16x8*)(ht + byte) = o;
    }
  } else {
    const u16* hin = (const u16*)hin_;
    const int c8 = tid & 31;               // constant per thread across iters
    float scr[8], shr[8];
    {
      float4 a0 = *(const float4*)(sc + c8 * 8);
      float4 a1 = *(const float4*)(sc + c8 * 8 + 4);
      float4 s0 = *(const float4*)(sh + c8 * 8);
      float4 s1 = *(const float4*)(sh + c8 * 8 + 4);
      scr[0]=a0.x; scr[1]=a0.y; scr[2]=a0.z; scr[3]=a0.w;
      scr[4]=a1.x; scr[5]=a1.y; scr[6]=a1.z; scr[7]=a1.w;
      shr[0]=s0.x; shr[1]=s0.y; shr[2]=s0.z; shr[3]=s0.w;
      shr[4]=s1.x; shr[5]=s1.y; shr[6]=s1.z; shr[7]=s1.w;
    }
    #pragma unroll
    for (int i = 0; i < 8; i++){
      int idx = tid + i * 512;
      int row = idx >> 5;
      u16x8 v = *(const u16x8*)(hin + (size_t)(g * NPG + row) * KIN + c8 * 8);
      u16x8 o;
      #pragma unroll
      for (int k = 0; k < 8; k++) o[k] = f2b(b2f(v[k]) * scr[k] + shr[k]);
      unsigned byte = ((unsigned)(row * (KIN * 2) + c8 * 16)) ^ ((unsigned)((row & 7) << 4));
      *(u16x8*)(ht + byte) = o;
    }
  }
  __syncthreads();

  // ---- GEMM1 (natural): G1 = h @ W1 -> G1T[c][n] ----
  {
    f32x4 acc[8][2] = {};
    #pragma unroll
    for (int kk = 0; kk < KIN / 32; kk++){
      bf16x8 bfr[2];
      #pragma unroll
      for (int nf = 0; nf < 2; nf++)
        bfr[nf] = *(const bf16x8*)(w1img + (size_t)(c0 + nf * 16 + l15) * KIN + kk * 32 + lk);
      bf16x8 af[8];
      #pragma unroll
      for (int mf = 0; mf < 8; mf++){
        int row = mf * 16 + l15;
        unsigned byte = ((unsigned)(row * (KIN * 2) + (kk * 32 + lk) * 2)) ^ ((unsigned)((row & 7) << 4));
        af[mf] = *(const bf16x8*)(ht + byte);
      }
      #pragma unroll
      for (int mf = 0; mf < 8; mf++)
        #pragma unroll
        for (int nf = 0; nf < 2; nf++)
          acc[mf][nf] = __builtin_amdgcn_mfma_f32_16x16x32_bf16(af[mf], bfr[nf], acc[mf][nf], 0, 0, 0);
    }
    #pragma unroll
    for (int mf = 0; mf < 8; mf++)
      #pragma unroll
      for (int nf = 0; nf < 2; nf++){
        int c = c0 + nf * 16 + l15;
        int n0 = mf * 16 + (lane >> 4) * 4;
        u16x4 o;
        #pragma unroll
        for (int j = 0; j < 4; j++) o[j] = f2b(acc[mf][nf][j]);
        unsigned byte = ((unsigned)(c * 256 + n0 * 2)) ^ ((unsigned)((c & 7) << 4));
        *(u16x4*)(g1t + byte) = o;
      }
  }

  // ---- agg GEMM (swapped): z1^T = G1^T @ (I+A)^T ----
  {
    f32x4 acc[8][2] = {};
    bf16x8 gfr[4][2];                      // own-wave G1T rows, prefetched
    #pragma unroll
    for (int kk = 0; kk < 4; kk++)
      #pragma unroll
      for (int cf = 0; cf < 2; cf++){
        int c = c0 + cf * 16 + l15;
        unsigned byte = ((unsigned)(c * 256 + (kk * 32 + lk) * 2)) ^ ((unsigned)((c & 7) << 4));
        gfr[kk][cf] = *(const bf16x8*)(g1t + byte);
      }
    #pragma unroll
    for (int kk = 0; kk < 4; kk++){
      bf16x8 bfA[8];
      #pragma unroll
      for (int nf = 0; nf < 8; nf++){
        int n = nf * 16 + l15;
        unsigned byte = ((unsigned)((n << 7) + kk * 32 + lk)) ^ ((unsigned)((n & 7) << 4));
        uint2 dd = *(const uint2*)(Ab + byte);
        bfA[nf] = u8x8_to_bf16x8(dd.x, dd.y);
      }
      #pragma unroll
      for (int nf = 0; nf < 8; nf++)
        #pragma unroll
        for (int cf = 0; cf < 2; cf++)
          acc[nf][cf] = __builtin_amdgcn_mfma_f32_16x16x32_bf16(gfr[kk][cf], bfA[nf], acc[nf][cf], 0, 0, 0);
    }
    __syncthreads();                       // all G1T reads done everywhere
    // z1 = relu(acc + b1) -> g1t region, row-major [n][256] swz
    #pragma unroll
    for (int nf = 0; nf < 8; nf++)
      #pragma unroll
      for (int cf = 0; cf < 2; cf++){
        int n = nf * 16 + l15;
        int cb = c0 + cf * 16 + (lane >> 4) * 4;
        float4 bv = *(const float4*)(b1 + cb);
        u16x4 o;
        o[0] = f2b(fmaxf(acc[nf][cf][0] + bv.x, 0.f));
        o[1] = f2b(fmaxf(acc[nf][cf][1] + bv.y, 0.f));
        o[2] = f2b(fmaxf(acc[nf][cf][2] + bv.z, 0.f));
        o[3] = f2b(fmaxf(acc[nf][cf][3] + bv.w, 0.f));
        unsigned byte = ((unsigned)(n * 512 + cb * 2)) ^ ((unsigned)((n & 7) << 4));
        *(u16x4*)(g1t + byte) = o;
      }
  }
  __syncthreads();

  // ---- GEMM2 (swapped): Y^T = W2^T @ z1^T -> global + BN stats ----
  {
    f32x4 acc[8][2] = {};
    #pragma unroll
    for (int kk = 0; kk < 8; kk++){
      bf16x8 bfr[2];
      #pragma unroll
      for (int cf = 0; cf < 2; cf++)
        bfr[cf] = *(const bf16x8*)(w2img + (size_t)(c0 + cf * 16 + l15) * 256 + kk * 32 + lk);
      bf16x8 zf[8];
      #pragma unroll
      for (int nf = 0; nf < 8; nf++){
        int n = nf * 16 + l15;
        unsigned byte = ((unsigned)(n * 512 + (kk * 32 + lk) * 2)) ^ ((unsigned)((n & 7) << 4));
        zf[nf] = *(const bf16x8*)(g1t + byte);
      }
      #pragma unroll
      for (int nf = 0; nf < 8; nf++)
        #pragma unroll
        for (int cf = 0; cf < 2; cf++)
          acc[nf][cf] = __builtin_amdgcn_mfma_f32_16x16x32_bf16(bfr[cf], zf[nf], acc[nf][cf], 0, 0, 0);
    }
    float sv[2][4] = {}, qv[2][4] = {};
    #pragma unroll
    for (int nf = 0; nf < 8; nf++)
      #pragma unroll
      for (int cf = 0; cf < 2; cf++){
        int n = nf * 16 + l15;
        int cb = c0 + cf * 16 + (lane >> 4) * 4;
        float4 bv = *(const float4*)(b2 + cb);
        u16x4 o;
        float v0 = fmaxf(acc[nf][cf][0] + bv.x, 0.f);
        float v1 = fmaxf(acc[nf][cf][1] + bv.y, 0.f);
        float v2 = fmaxf(acc[nf][cf][2] + bv.z, 0.f);
        float v3 = fmaxf(acc[nf][cf][3] + bv.w, 0.f);
        o[0] = f2b(v0); o[1] = f2b(v1); o[2] = f2b(v2); o[3] = f2b(v3);
        sv[cf][0] += v0; sv[cf][1] += v1; sv[cf][2] += v2; sv[cf][3] += v3;
        qv[cf][0] += v0 * v0; qv[cf][1] += v1 * v1; qv[cf][2] += v2 * v2; qv[cf][3] += v3 * v3;
        *(u16x4*)(Y + (size_t)(g * NPG + n) * HD + cb) = o;
      }
    #pragma unroll
    for (int m = 1; m <= 8; m <<= 1)
      #pragma unroll
      for (int cf = 0; cf < 2; cf++)
        #pragma unroll
        for (int j = 0; j < 4; j++){
          sv[cf][j] += __shfl_xor(sv[cf][j], m);
          qv[cf][j] += __shfl_xor(qv[cf][j], m);
        }
    if (l15 == 0){
      int jb = (lane >> 4) * 4;
      #pragma unroll
      for (int cf = 0; cf < 2; cf++)
        #pragma unroll
        for (int j = 0; j < 4; j++){
          int col = c0 + cf * 16 + jb + j;
          pS[(size_t)col * NB + g] = sv[cf][j];
          pQ[(size_t)col * NB + g] = qv[cf][j];
        }
    }
  }
}

// BN finalize: per-feature mean/var over N -> scale/shift.
__global__ void __launch_bounds__(64) bnfin_kernel(const float* __restrict__ pS,
    const float* __restrict__ pQ, const float* __restrict__ gma,
    const float* __restrict__ bta, float* __restrict__ scale, float* __restrict__ shift)
{
  int c = blockIdx.x, lane = threadIdx.x;
  float s = 0.f, q = 0.f;
  for (int i = lane; i < NB; i += 64){ s += pS[(size_t)c * NB + i]; q += pQ[(size_t)c * NB + i]; }
  for (int m = 32; m; m >>= 1){ s += __shfl_xor(s, m); q += __shfl_xor(q, m); }
  if (lane == 0){
    float mu = s * (1.0f / NN);
    float var = q * (1.0f / NN) - mu * mu;
    float scv = gma[c] * rsqrtf(var + BN_EPS);
    scale[c] = scv;
    shift[c] = bta[c] - mu * scv;
  }
}

// ---------------------------------------------------------------------------
// Fused tail per graph (unchanged from round 6).
// ---------------------------------------------------------------------------
template<int K>
__device__ __forceinline__ void mm_frag(const u16* Alds,
    const u16* __restrict__ wimg, int lane, int c0, f32x4 (&acc)[8][2])
{
  const int l15 = lane & 15, lk = (lane >> 4) * 8;
  bf16x8 bfr[K / 32][2];
  #pragma unroll
  for (int kk = 0; kk < K / 32; kk++)
    #pragma unroll
    for (int nf = 0; nf < 2; nf++)
      bfr[kk][nf] = *(const bf16x8*)(wimg + (size_t)(c0 + nf * 16 + l15) * K + kk * 32 + lk);
  #pragma unroll
  for (int kk = 0; kk < K / 32; kk++){
    bf16x8 af[8];
    #pragma unroll
    for (int mf = 0; mf < 8; mf++){
      int row = mf * 16 + l15;
      unsigned byte = ((unsigned)(row * (K * 2) + (kk * 32 + lk) * 2)) ^ (unsigned)((row & 7) << 4);
      af[mf] = *(const bf16x8*)((const char*)Alds + byte);
    }
    #pragma unroll
    for (int mf = 0; mf < 8; mf++)
      #pragma unroll
      for (int nf = 0; nf < 2; nf++)
        acc[mf][nf] = __builtin_amdgcn_mfma_f32_16x16x32_bf16(af[mf], bfr[kk][nf], acc[mf][nf], 0, 0, 0);
  }
}

__global__ void __launch_bounds__(512) final_kernel(
    const u16* __restrict__ hin, const int* __restrict__ ei,
    const float* __restrict__ sc, const float* __restrict__ sh,
    const u16* __restrict__ c1img, const float* __restrict__ c1b,
    const float* __restrict__ c2w, const float* __restrict__ c2b,
    const float* __restrict__ l1w, const float* __restrict__ l1b,
    const float* __restrict__ l2w, const float* __restrict__ l2b,
    float* __restrict__ outLog, float* __restrict__ outSub,
    float* __restrict__ outGraph, float* __restrict__ outPen)
{
  __shared__ u16 ht[NPG * HD];
  __shared__ u16 esd[EPG];
  __shared__ float aL[NPG * 2];
  __shared__ float scratch[2048];
  __shared__ float subL[256];
  __shared__ float wred[8][4];
  const int g = blockIdx.x, tid = threadIdx.x;
  const int lane = tid & 63, wid = tid >> 6;

  if (tid < 256){ scratch[tid] = sc[tid]; scratch[256 + tid] = sh[tid]; }
  {
    int s = ei[g * EPG + tid] & (NPG - 1);
    int d = ei[NE + g * EPG + tid] & (NPG - 1);
    esd[tid] = (u16)(s | (d << 8));
  }
  __syncthreads();

  #pragma unroll
  for (int i = 0; i < 8; i++){
    int idx = tid + i * 512;
    int row = idx >> 5, c8 = idx & 31;
    u16x8 v = *(const u16x8*)(hin + (size_t)(g * NPG + row) * HD + c8 * 8);
    u16x8 o;
    #pragma unroll
    for (int k = 0; k < 8; k++)
      o[k] = f2b(b2f(v[k]) * scratch[c8 * 8 + k] + scratch[256 + c8 * 8 + k]);
    unsigned byte = ((unsigned)(row * 512 + c8 * 16)) ^ (unsigned)((row & 7) << 4);
    *(u16x8*)((char*)ht + byte) = o;
  }
  __syncthreads();

  const int c0 = wid * 32;
  const int l15 = lane & 15;

  {
    f32x4 acct[8][2] = {};
    mm_frag<HD>(ht, c1img, lane, c0, acct);
    const int col0 = c0 + l15, col1 = c0 + 16 + l15;
    const float bv0 = c1b[col0], bv1 = c1b[col1];
    const float w00 = c2w[col0 * 2], w01 = c2w[col0 * 2 + 1];
    const float w10 = c2w[col1 * 2], w11 = c2w[col1 * 2 + 1];
    #pragma unroll
    for (int mf = 0; mf < 8; mf++)
      #pragma unroll
      for (int j = 0; j < 4; j++){
        float t0 = ftanh(acct[mf][0][j] + bv0);
        float t1 = ftanh(acct[mf][1][j] + bv1);
        float p0 = t0 * w00 + t1 * w10;
        float p1 = t0 * w01 + t1 * w11;
        p0 += __shfl_xor(p0, 1); p0 += __shfl_xor(p0, 2);
        p0 += __shfl_xor(p0, 4); p0 += __shfl_xor(p0, 8);
        p1 += __shfl_xor(p1, 1); p1 += __shfl_xor(p1, 2);
        p1 += __shfl_xor(p1, 4); p1 += __shfl_xor(p1, 8);
        if (l15 == 0){
          int row = mf * 16 + (lane >> 4) * 4 + j;
          scratch[row * 16 + wid * 2]     = p0;
          scratch[row * 16 + wid * 2 + 1] = p1;
        }
      }
  }
  __syncthreads();

  {
    int row = tid >> 2, part = tid & 3;
    float4 v = *(const float4*)&scratch[row * 16 + part * 4];
    float p0 = v.x + v.z, p1 = v.y + v.w;
    p0 += __shfl_xor(p0, 1); p0 += __shfl_xor(p0, 2);
    p1 += __shfl_xor(p1, 1); p1 += __shfl_xor(p1, 2);
    if (part == 0){
      p0 += c2b[0]; p1 += c2b[1];
      float mx = fmaxf(p0, p1);
      float e0 = expf(p0 - mx), e1 = expf(p1 - mx);
      float inv = 1.f / (e0 + e1);
      aL[row * 2] = e0 * inv; aL[row * 2 + 1] = e1 * inv;
    }
  }
  __syncthreads();

  {
    int v = esd[tid];
    int sE = v & 255, dE = v >> 8;
    float as0 = aL[sE * 2], as1 = aL[sE * 2 + 1];
    float ad0 = aL[dE * 2], ad1 = aL[dE * 2 + 1];
    float m00 = as0 * ad0, m01 = as0 * ad1, m10 = as1 * ad0, m11 = as1 * ad1;
    #pragma unroll
    for (int m = 1; m < 64; m <<= 1){
      m00 += __shfl_xor(m00, m); m01 += __shfl_xor(m01, m);
      m10 += __shfl_xor(m10, m); m11 += __shfl_xor(m11, m);
    }
    if (lane == 0){ wred[wid][0] = m00; wred[wid][1] = m01; wred[wid][2] = m10; wred[wid][3] = m11; }
  }
  {
    const int part = tid >> 8, c = tid & 255;
    float sb = 0.f, gs = 0.f;
    #pragma unroll 8
    for (int i = 0; i < 64; i++){
      int n = part * 64 + i;
      unsigned byte = ((unsigned)(n * 512 + c * 2)) ^ (unsigned)((n & 7) << 4);
      float v = b2f(*(const u16*)((const char*)ht + byte));
      sb += aL[n * 2] * v; gs += v;
    }
    __syncthreads();
    scratch[part * 512 + c] = sb;
    scratch[part * 512 + 256 + c] = gs;
  }
  __syncthreads();
  if (tid < 256){
    float sb = scratch[tid] + scratch[512 + tid];
    float gs = scratch[256 + tid] + scratch[768 + tid];
    subL[tid] = sb;
    outSub[(size_t)g * HD + tid] = sb;
    outGraph[(size_t)g * HD + tid] = gs * (1.f / NPG);
  }
  if (tid == 0){
    float m00 = 0, m01 = 0, m10 = 0, m11 = 0;
    for (int w = 0; w < 8; w++){ m00 += wred[w][0]; m01 += wred[w][1]; m10 += wred[w][2]; m11 += wred[w][3]; }
    float r0 = fmaxf(fabsf(m00) + fabsf(m01), 1e-12f);
    float r1 = fmaxf(fabsf(m10) + fabsf(m11), 1e-12f);
    float d0 = m00 / r0 - 1.f, d1 = m11 / r1 - 1.f;
    atomicAdd(outPen, 0.5f * (d0 * d0 + d1 * d1) * (1.0f / NB));
  }
  __syncthreads();

  {
    const int ph = tid >> 8, c = tid & 255;
    float z = 0.f;
    for (int k = ph * 128; k < ph * 128 + 128; k++)
      z += subL[k] * l1w[(size_t)k * HD + c];
    scratch[ph * 256 + c] = z;
  }
  __syncthreads();
  if (tid < 256){
    float z = fmaxf(scratch[tid] + scratch[256 + tid] + l1b[tid], 0.f);
    float o0 = z * l2w[tid * 2], o1 = z * l2w[tid * 2 + 1];
    #pragma unroll
    for (int m = 1; m < 64; m <<= 1){ o0 += __shfl_xor(o0, m); o1 += __shfl_xor(o1, m); }
    if (lane == 0){ wred[wid][0] = o0; wred[wid][1] = o1; }
  }
  __syncthreads();
  if (tid == 0){
    float o0 = wred[0][0] + wred[1][0] + wred[2][0] + wred[3][0] + l2b[0];
    float o1 = wred[0][1] + wred[1][1] + wred[2][1] + wred[3][1] + l2b[1];
    float mx = fmaxf(o0, o1);
    float lse = mx + logf(expf(o0 - mx) + expf(o1 - mx));
    outLog[(size_t)g * 2] = o0 - lse;
    outLog[(size_t)g * 2 + 1] = o1 - lse;
  }
}

// ---------------------------------------------------------------------------
extern "C" void kernel_launch(void* const* d_in, const int* in_sizes, int n_in,
                              void* d_out, int out_size, void* d_ws, size_t ws_size,
                              hipStream_t stream)
{
  (void)in_sizes; (void)n_in; (void)out_size; (void)ws_size;
  const float* x    = (const float*)d_in[0];
  const int*   ei   = (const int*)  d_in[1];
  const float* w0_1 = (const float*)d_in[3];
  const float* b0_1 = (const float*)d_in[4];
  const float* w0_2 = (const float*)d_in[5];
  const float* b0_2 = (const float*)d_in[6];
  const float* g0   = (const float*)d_in[7];
  const float* be0  = (const float*)d_in[8];
  const float* wl1  = (const float*)d_in[9];
  const float* bl1  = (const float*)d_in[10];
  const float* wl2  = (const float*)d_in[11];
  const float* bl2  = (const float*)d_in[12];
  const float* gl   = (const float*)d_in[13];
  const float* bel  = (const float*)d_in[14];
  const float* c1w  = (const float*)d_in[15];
  const float* c1b  = (const float*)d_in[16];
  const float* c2w  = (const float*)d_in[17];
  const float* c2b  = (const float*)d_in[18];
  const float* l1w  = (const float*)d_in[19];
  const float* l1b  = (const float*)d_in[20];
  const float* l2w  = (const float*)d_in[21];
  const float* l2b  = (const float*)d_in[22];
  float* out = (float*)d_out;

  char* cur = (char*)d_ws;
  auto carve = [&](size_t bytes) -> void* {
    void* p = (void*)cur; cur += (bytes + 255) & ~(size_t)255; return p;
  };
  u16* B0    = (u16*)carve((size_t)NN * HD * 2);
  u16* B1    = (u16*)carve((size_t)NN * HD * 2);
  u16* i01   = (u16*)carve((size_t)128 * 256 * 2);
  u16* i02   = (u16*)carve((size_t)256 * 256 * 2);
  u16* il1a  = (u16*)carve((size_t)256 * 256 * 2);
  u16* il1b  = (u16*)carve((size_t)256 * 256 * 2);
  u16* il2a  = (u16*)carve((size_t)256 * 256 * 2);
  u16* il2b  = (u16*)carve((size_t)256 * 256 * 2);
  u16* ic1   = (u16*)carve((size_t)256 * 256 * 2);
  float* pS  = (float*)carve((size_t)256 * NB * 4);
  float* pQ  = (float*)carve((size_t)256 * NB * 4);
  float* bsc = (float*)carve(256 * 4);
  float* bsh = (float*)carve(256 * 4);

  float* outPen = out + 1024 + 2 * NB * HD;

  pack_all<<<dim3(256, 7), 256, 0, stream>>>(w0_1, w0_2, wl1, wl2, c1w,
                                             i01, i02, il1a, il1b, il2a, il2b, ic1);
  hipMemsetAsync((void*)outPen, 0, 4, stream);

  layer_kernel<128, 0><<<NB, 512, 0, stream>>>((const void*)x, ei, nullptr, nullptr,
                                               i01, b0_1, i02, b0_2, B0, pS, pQ);
  bnfin_kernel<<<256, 64, 0, stream>>>(pS, pQ, g0, be0, bsc, bsh);

  layer_kernel<256, 1><<<NB, 512, 0, stream>>>((const void*)B0, ei, bsc, bsh,
                                               il1a, bl1, il2a, bl2, B1, pS, pQ);
  bnfin_kernel<<<256, 64, 0, stream>>>(pS, pQ, gl, bel, bsc, bsh);

  layer_kernel<256, 1><<<NB, 512, 0, stream>>>((const void*)B1, ei, bsc, bsh,
                                               il1b, bl1 + 256, il2b, bl2 + 256, B0, pS, pQ);
  bnfin_kernel<<<256, 64, 0, stream>>>(pS, pQ, gl + 256, bel + 256, bsc, bsh);

  final_kernel<<<NB, 512, 0, stream>>>(B0, ei, bsc, bsh, ic1, c1b, c2w, c2b,
                                       l1w, l1b, l2w, l2b,
                                       out, out + 1024, out + 1024 + NB * HD, outPen);
}